// Round 4
// baseline (1233.478 us; speedup 1.0000x reference)
//
#include <hip/hip_runtime.h>
#include <cstdint>
#include <cstddef>

// ---------------------------------------------------------------------------
// SOARALinear: out = x @ W^T + bias + x @ V^T @ R_V @ diag(S) @ R_U^T @ U^T
// Collapsed:   Wct = W + U @ (R_U diag(S) R_V^T) @ V ;  out = x @ Wct^T + bias
// Large GEMMs: 256x256 tile, BK=64, 8 waves. Free-run K-tile body:
//   ONE s_barrier + ONE counted vmcnt(8) per K-tile; stage 4 half-tiles of
//   t+1 right after the barrier (a full K-tile of latency slack); the whole
//   ds_read+MFMA body is one compiler-scheduled region (counted lgkm waits).
//   Even/odd waves run quadrants in opposite order -> anti-phase on each
//   SIMD: one wave's MFMA burst covers the other's LDS-read burst.
// LDS XOR-swizzled (0 bank conflicts, measured R1-R3).
// Small GEMMs keep the proven 128x128 kernel.
// ---------------------------------------------------------------------------

typedef __bf16 bf16x8 __attribute__((ext_vector_type(8)));
typedef float floatx4 __attribute__((ext_vector_type(4)));
typedef unsigned short ushortx8 __attribute__((ext_vector_type(8)));

__device__ __forceinline__ unsigned short f2bf(float f) {
    unsigned int u = __builtin_bit_cast(unsigned int, f);
    u += 0x7FFFu + ((u >> 16) & 1u);   // round-to-nearest-even
    return (unsigned short)(u >> 16);
}

__device__ __forceinline__ void gld_lds16(const void* g, void* l) {
    __builtin_amdgcn_global_load_lds(
        (const __attribute__((address_space(1))) void*)g,
        (__attribute__((address_space(3))) void*)l,
        16, 0, 0);
}

__device__ __forceinline__ bf16x8 ldsv(const char* p) {
    return __builtin_bit_cast(bf16x8, *(const ushortx8*)p);
}

#define MFMA_BF16(a, b, c) __builtin_amdgcn_mfma_f32_16x16x32_bf16((a), (b), (c), 0, 0, 0)
#define SCHED0() __builtin_amdgcn_sched_barrier(0)

// ---------------------------------------------------------------------------
// Butterfly rows: R = C_0 C_1 ... C_9 (d=1024).
// mat 0 -> RVs (R_V with column k scaled by S[k]) bf16 ; mat 1 -> R_U bf16
// ---------------------------------------------------------------------------
__global__ __launch_bounds__(256) void butterfly_rows_kernel(
    const float* __restrict__ thetas_v, const float* __restrict__ thetas_u,
    const float* __restrict__ S,
    unsigned short* __restrict__ RVsb, unsigned short* __restrict__ RUb)
{
    const int d = 1024;
    __shared__ float w[1024];
    const int b   = blockIdx.x;
    const int mat = b >> 10;        // 0: V, 1: U
    const int row = b & 1023;
    const float* th = mat ? thetas_u : thetas_v;
    const int t = threadIdx.x;

    for (int i = t; i < d; i += 256) w[i] = (i == row) ? 1.f : 0.f;
    __syncthreads();

    for (int j = 0; j < 10; ++j) {
        const int sh = 9 - j;
        const int halfm1 = (1 << sh) - 1;
        for (int i = t; i < d / 2; i += 256) {
            const int blk = i >> sh;
            const int off = i & halfm1;
            const int p = (blk << (sh + 1)) + off;
            const int q = p + (halfm1 + 1);
            const float theta = th[j * (d / 2) + i];
            float s, c;
            __sincosf(theta, &s, &c);
            const float wp = w[p], wq = w[q];
            w[p] = c * wp + s * wq;
            w[q] = -s * wp + c * wq;
        }
        __syncthreads();
    }

    if (mat == 0) {
        for (int i = t; i < d; i += 256) RVsb[row * d + i] = f2bf(w[i] * S[i]);
    } else {
        for (int i = t; i < d; i += 256) RUb[row * d + i] = f2bf(w[i]);
    }
}

// ---------------------------------------------------------------------------
__global__ __launch_bounds__(256) void cvt_f32_bf16_x8(
    const float* __restrict__ src, unsigned short* __restrict__ dst)
{
    const size_t i = ((size_t)blockIdx.x * 256 + threadIdx.x) * 8;
    float4 a = *(const float4*)(src + i);
    float4 b = *(const float4*)(src + i + 4);
    ushortx8 o;
    o[0] = f2bf(a.x); o[1] = f2bf(a.y); o[2] = f2bf(a.z); o[3] = f2bf(a.w);
    o[4] = f2bf(b.x); o[5] = f2bf(b.y); o[6] = f2bf(b.z); o[7] = f2bf(b.w);
    *(ushortx8*)(dst + i) = o;
}

// ---------------------------------------------------------------------------
__global__ __launch_bounds__(256) void transpose_to_bf16(
    const float* __restrict__ src, unsigned short* __restrict__ dst,
    int rows, int cols)
{
    __shared__ float tile[32][33];
    const int tx = threadIdx.x & 31, ty = threadIdx.x >> 5;
    const int c0 = blockIdx.x * 32, r0 = blockIdx.y * 32;
    for (int i = 0; i < 32; i += 8)
        tile[ty + i][tx] = src[(size_t)(r0 + ty + i) * cols + c0 + tx];
    __syncthreads();
    for (int i = 0; i < 32; i += 8)
        dst[(size_t)(c0 + ty + i) * rows + r0 + tx] = f2bf(tile[tx][ty + i]);
}

// ---------------------------------------------------------------------------
// Small NT GEMM (the two 1024-class rotation GEMMs): 128x128 tile.
// ---------------------------------------------------------------------------
template <int EPI>
__global__ __launch_bounds__(256) void gemm_nt(
    const unsigned short* __restrict__ A,
    const unsigned short* __restrict__ B,
    float* __restrict__ Cf,
    unsigned short* __restrict__ Cb,
    const float* __restrict__ extra,
    int M, int N, int K)
{
    __shared__ __align__(16) unsigned short As[128 * 32];
    __shared__ __align__(16) unsigned short Bs[128 * 32];

    const int tid  = threadIdx.x;
    const int lane = tid & 63;
    const int wave = tid >> 6;
    const int wm = wave >> 1, wn = wave & 1;

    const int m0 = blockIdx.y * 128;
    const int n0 = blockIdx.x * 128;

    const int srow = wave * 32 + (lane >> 2);
    const int scol = (lane & 3) * 8;

    const unsigned short* gA = A + (size_t)(m0 + srow) * K + scol;
    const unsigned short* gB = B + (size_t)(n0 + srow) * K + scol;
    unsigned short* lA = As + wave * 32 * 32;
    unsigned short* lB = Bs + wave * 32 * 32;

    floatx4 acc[4][4];
#pragma unroll
    for (int i = 0; i < 4; ++i)
#pragma unroll
        for (int j = 0; j < 4; ++j) acc[i][j] = (floatx4)0.f;

    const int ar = lane & 15;
    const int ak = (lane >> 4) * 8;

    for (int kk = 0; kk < K; kk += 32) {
        gld_lds16(gA + kk, lA);
        gld_lds16(gA + kk + (size_t)16 * K, lA + 512);
        gld_lds16(gB + kk, lB);
        gld_lds16(gB + kk + (size_t)16 * K, lB + 512);
        __syncthreads();

        bf16x8 af[4], bfr[4];
#pragma unroll
        for (int tm = 0; tm < 4; ++tm)
            af[tm] = __builtin_bit_cast(bf16x8,
                *(const ushortx8*)&As[(wm * 64 + tm * 16 + ar) * 32 + ak]);
#pragma unroll
        for (int tn = 0; tn < 4; ++tn)
            bfr[tn] = __builtin_bit_cast(bf16x8,
                *(const ushortx8*)&Bs[(wn * 64 + tn * 16 + ar) * 32 + ak]);
#pragma unroll
        for (int tm = 0; tm < 4; ++tm)
#pragma unroll
            for (int tn = 0; tn < 4; ++tn)
                acc[tm][tn] = MFMA_BF16(af[tm], bfr[tn], acc[tm][tn]);
        __syncthreads();
    }

#pragma unroll
    for (int tm = 0; tm < 4; ++tm) {
#pragma unroll
        for (int tn = 0; tn < 4; ++tn) {
#pragma unroll
            for (int r = 0; r < 4; ++r) {
                const int row = m0 + wm * 64 + tm * 16 + (lane >> 4) * 4 + r;
                const int col = n0 + wn * 64 + tn * 16 + (lane & 15);
                const float v = acc[tm][tn][r];
                if (EPI == 1) {
                    Cf[(size_t)row * N + col] = v + extra[col];
                } else if (EPI == 2) {
                    Cb[(size_t)row * N + col] = f2bf(v);
                } else {
                    Cb[(size_t)row * N + col] = f2bf(v + extra[(size_t)row * N + col]);
                }
            }
        }
    }
}

// ---------------------------------------------------------------------------
// Large NT GEMM: 256x256 tile, BK=64, 512 threads (8 waves, 2M x 4N).
// LDS: As/Bs[2 dbuf][2 half][128][64] bf16, XOR-swizzled (linear dest +
// inverse-swizzled global source + swizzled ds_read).
// Per K-tile: s_barrier; stage 4 half-tiles of t+1 (other buffer);
// vmcnt(8) (waits only on tile-t's loads, issued a full K-tile earlier);
// then a single free-run read+MFMA region (compiler counted-lgkm pipelines
// ds_read under MFMA). Even waves: Q00,Q01,Q11,Q10; odd waves reversed ->
// anti-phase read/MFMA bursts on each SIMD.
// EPI 1: f32 out + bias[col] ;  EPI 3: bf16 out + f32 extra[M,N]
// M,N multiples of 256; K multiple of 64, K/64 >= 2.
// ---------------------------------------------------------------------------
#define RD_AF0() do { _Pragma("unroll") \
    for (int mf = 0; mf < 4; ++mf) { \
        af0[mf][0] = ldsv(Ad + arb + mf * 2048 + ca0); \
        af0[mf][1] = ldsv(Ad + arb + mf * 2048 + ca1); } } while (0)
#define RD_AF1() do { _Pragma("unroll") \
    for (int mf = 0; mf < 4; ++mf) { \
        af1[mf][0] = ldsv(Ad + 16384 + arb + mf * 2048 + ca0); \
        af1[mf][1] = ldsv(Ad + 16384 + arb + mf * 2048 + ca1); } } while (0)
#define RD_B0() do { _Pragma("unroll") \
    for (int nf = 0; nf < 2; ++nf) { \
        b0[nf][0] = ldsv(Bd + brb + nf * 2048 + ca0); \
        b0[nf][1] = ldsv(Bd + brb + nf * 2048 + ca1); } } while (0)
#define RD_B1() do { _Pragma("unroll") \
    for (int nf = 0; nf < 2; ++nf) { \
        b1[nf][0] = ldsv(Bd + 16384 + brb + nf * 2048 + ca0); \
        b1[nf][1] = ldsv(Bd + 16384 + brb + nf * 2048 + ca1); } } while (0)
#define MMQ(A_, B_, mo, no) do { \
    __builtin_amdgcn_s_setprio(1); \
    _Pragma("unroll") \
    for (int mf = 0; mf < 4; ++mf) \
        _Pragma("unroll") \
        for (int nf = 0; nf < 2; ++nf) { \
            acc[(mo) + mf][(no) + nf] = MFMA_BF16(A_[mf][0], B_[nf][0], acc[(mo) + mf][(no) + nf]); \
            acc[(mo) + mf][(no) + nf] = MFMA_BF16(A_[mf][1], B_[nf][1], acc[(mo) + mf][(no) + nf]); } \
    __builtin_amdgcn_s_setprio(0); } while (0)

template <int EPI>
__global__ __launch_bounds__(512, 2) void gemm256(
    const unsigned short* __restrict__ A,
    const unsigned short* __restrict__ B,
    float* __restrict__ Cf,
    unsigned short* __restrict__ Cb,
    const float* __restrict__ extra,
    int M, int N, int K, int swz_on)
{
    __shared__ __align__(16) unsigned short As[2][2][128][64];
    __shared__ __align__(16) unsigned short Bs[2][2][128][64];

    const int tid  = threadIdx.x;
    const int lane = tid & 63;
    const int wave = tid >> 6;
    const int wm = wave >> 2;      // 0..1
    const int wn = wave & 3;       // 0..3

    int bx = blockIdx.x, by = blockIdx.y;
    if (swz_on) {                  // XCD-aware bijective swizzle (nwg % 8 == 0)
        const int gx  = gridDim.x;
        const int nwg = gx * gridDim.y;
        const int f   = by * gx + bx;
        const int g   = (f & 7) * (nwg >> 3) + (f >> 3);
        bx = g % gx;
        by = g / gx;
    }
    const int m0 = by * 256;
    const int n0 = bx * 256;

    // ---- staging: linear LDS dest, inverse-swizzled global source
    const int srow  = tid >> 3;                          // 0..63 in a 64-row slab
    const int scolb = (tid & 7) << 4;                    // physical col byte
    const int scol  = (scolb ^ ((srow & 7) << 4)) >> 1;  // logical col (elems)
    const unsigned short* gA = A + (size_t)(m0 + srow) * K + scol;
    const unsigned short* gB = B + (size_t)(n0 + srow) * K + scol;
    char* lA = (char*)As + (wave << 10);                 // wave-uniform base
    char* lB = (char*)Bs + (wave << 10);
    const size_t rs64 = (size_t)64 * K;                  // 64-row stride

    // stage half-tile h (A or B) of K-tile src_t into buffer dbuf
    auto stA = [&](int src_t, int dbuf, int h) {
        const unsigned short* s = gA + (size_t)h * 2 * rs64 + (size_t)src_t * 64;
        char* l = lA + dbuf * 32768 + h * 16384;
        gld_lds16(s, l);
        gld_lds16(s + rs64, l + 8192);
    };
    auto stB = [&](int src_t, int dbuf, int h) {
        const unsigned short* s = gB + (size_t)h * 2 * rs64 + (size_t)src_t * 64;
        char* l = lB + dbuf * 32768 + h * 16384;
        gld_lds16(s, l);
        gld_lds16(s + rs64, l + 8192);
    };

    // ---- fragment read addressing (swizzled)
    const int fr  = lane & 15;
    const int kg  = lane >> 4;                 // 0..3 -> K elems 8*kg
    const int swz = (fr & 7) << 4;
    const int ca0 = (kg << 4) ^ swz;           // K-step 0 col byte
    const int ca1 = (64 + (kg << 4)) ^ swz;    // K-step 1 col byte
    const int arb = (wm * 64 + fr) * 128;      // A byte row base within half
    const int brb = (wn * 32 + fr) * 128;      // B byte row base within half

    floatx4 acc[8][4];
#pragma unroll
    for (int i = 0; i < 8; ++i)
#pragma unroll
        for (int j = 0; j < 4; ++j) acc[i][j] = (floatx4)0.f;

    const int nkt = K >> 6;

    // prologue: stage K-tile 0 into buffer 0 (8 loads in flight)
    stA(0, 0, 0); stB(0, 0, 0); stB(0, 0, 1); stA(0, 0, 1);

    for (int t = 0; t < nkt; ++t) {
        const int cb = t & 1, nb = cb ^ 1;
        const char* Ad = (const char*)As + cb * 32768;
        const char* Bd = (const char*)Bs + cb * 32768;

        // tile entry: barrier (all waves done reading buf nb), stage t+1,
        // counted wait covering exactly tile-t's 8 staging loads.
        __builtin_amdgcn_s_barrier();
        if (t + 1 < nkt) {
            stA(t + 1, nb, 0); stB(t + 1, nb, 0);
            stB(t + 1, nb, 1); stA(t + 1, nb, 1);
            asm volatile("s_waitcnt vmcnt(8)" ::: "memory");
        } else {
            asm volatile("s_waitcnt vmcnt(0)" ::: "memory");
        }
        SCHED0();

        bf16x8 af0[4][2], af1[4][2], b0[2][2], b1[2][2];

        if ((wave & 1) == 0) {
            // forward: Q00, Q01, Q11, Q10
            RD_AF0(); RD_B0();
            MMQ(af0, b0, 0, 0);
            RD_B1();
            MMQ(af0, b1, 0, 2);
            RD_AF1();
            MMQ(af1, b1, 4, 2);
            MMQ(af1, b0, 4, 0);
        } else {
            // reversed: Q11, Q10, Q00, Q01 (anti-phase with even waves)
            RD_AF1(); RD_B1();
            MMQ(af1, b1, 4, 2);
            RD_B0();
            MMQ(af1, b0, 4, 0);
            RD_AF0();
            MMQ(af0, b0, 0, 0);
            MMQ(af0, b1, 0, 2);
        }
    }

    // epilogue: C/D layout col = lane&15, row = (lane>>4)*4 + r
    const int er4 = (lane >> 4) << 2;
    const int ec  = lane & 15;
#pragma unroll
    for (int Mq = 0; Mq < 2; ++Mq)
#pragma unroll
        for (int mf = 0; mf < 4; ++mf)
#pragma unroll
            for (int Nq = 0; Nq < 2; ++Nq)
#pragma unroll
                for (int nf = 0; nf < 2; ++nf)
#pragma unroll
                    for (int r = 0; r < 4; ++r) {
                        const int row = m0 + Mq * 128 + wm * 64 + mf * 16 + er4 + r;
                        const int col = n0 + Nq * 128 + wn * 32 + nf * 16 + ec;
                        const float v = acc[Mq * 4 + mf][Nq * 2 + nf][r];
                        if (EPI == 1) {
                            Cf[(size_t)row * N + col] = v + extra[col];
                        } else {
                            Cb[(size_t)row * N + col] = f2bf(v + extra[(size_t)row * N + col]);
                        }
                    }
    (void)M;
}

// ---------------------------------------------------------------------------
extern "C" void kernel_launch(void* const* d_in, const int* in_sizes, int n_in,
                              void* d_out, int out_size, void* d_ws, size_t ws_size,
                              hipStream_t stream)
{
    const int NB = 16384, DIN = 4096, DOUT = 4096, R = 1024;

    const float* x    = (const float*)d_in[0];
    const float* W    = (const float*)d_in[1];
    const float* bias = (const float*)d_in[2];
    const float* U    = (const float*)d_in[3];
    const float* S    = (const float*)d_in[4];
    const float* V    = (const float*)d_in[5];
    const float* th_u = (const float*)d_in[6];
    const float* th_v = (const float*)d_in[7];
    float* out = (float*)d_out;

    char* ws = (char*)d_ws;
    size_t off = 0;
    auto alloc = [&](size_t bytes) {
        char* p = ws + off;
        off += (bytes + 255) & ~(size_t)255;
        return p;
    };
    unsigned short* Xb   = (unsigned short*)alloc((size_t)NB * DIN * 2);
    unsigned short* Wctb = (unsigned short*)alloc((size_t)DOUT * DIN * 2);
    unsigned short* RVsb = (unsigned short*)alloc((size_t)R * R * 2);
    unsigned short* RUb  = (unsigned short*)alloc((size_t)R * R * 2);
    unsigned short* Tb   = (unsigned short*)alloc((size_t)R * R * 2);
    unsigned short* Ub   = (unsigned short*)alloc((size_t)DOUT * R * 2);
    unsigned short* Gb   = (unsigned short*)alloc((size_t)DOUT * R * 2);
    unsigned short* Vtb  = (unsigned short*)alloc((size_t)DIN * R * 2);
    if (off > ws_size) return;

    // 1. Butterfly rotations -> RVs (S-scaled) bf16, RU bf16
    butterfly_rows_kernel<<<2048, 256, 0, stream>>>(th_v, th_u, S, RVsb, RUb);

    // 2. Converts: x -> bf16, U -> bf16, V -> V^T bf16
    cvt_f32_bf16_x8<<<(NB * (size_t)DIN) / 2048, 256, 0, stream>>>(x, Xb);
    cvt_f32_bf16_x8<<<((size_t)DOUT * R) / 2048, 256, 0, stream>>>(U, Ub);
    transpose_to_bf16<<<dim3(DIN / 32, R / 32), 256, 0, stream>>>(V, Vtb, R, DIN);

    // 3. T[b,a] = sum_k RVs[b,k] * RU[a,k]
    gemm_nt<2><<<dim3(R / 128, R / 128), 256, 0, stream>>>(
        RVsb, RUb, nullptr, Tb, nullptr, R, R, R);

    // 4. G[o,b] = sum_a U[o,a] * T[b,a]
    gemm_nt<2><<<dim3(R / 128, DOUT / 128), 256, 0, stream>>>(
        Ub, Tb, nullptr, Gb, nullptr, DOUT, R, R);

    // 5. Wct[o,i] = W[o,i] + sum_b G[o,b] * Vt[i,b]   (256-tile, EPI3)
    gemm256<3><<<dim3(DIN / 256, DOUT / 256), 512, 0, stream>>>(
        Gb, Vtb, nullptr, Wctb, W, DOUT, DIN, R, 0);

    // 6. out[n,o] = sum_i Xb[n,i] * Wctb[o,i] + bias[o] (256-tile, EPI1, XCD swz)
    gemm256<1><<<dim3(DOUT / 256, NB / 256), 512, 0, stream>>>(
        Xb, Wctb, out, nullptr, bias, NB, DOUT, DIN, 1);
}

// Round 5
// 1074.666 us; speedup vs baseline: 1.1478x; 1.1478x over previous
//
#include <hip/hip_runtime.h>
#include <cstdint>
#include <cstddef>

// ---------------------------------------------------------------------------
// SOARALinear: out = x @ W^T + bias + x @ V^T @ R_V @ diag(S) @ R_U^T @ U^T
// Collapsed:   Wct = W + U @ (R_U diag(S) R_V^T) @ V ;  out = x @ Wct^T + bias
// Large GEMMs: 256x256 tile, BK=64, 8 waves, m201-faithful 4-phase schedule:
//   per phase {ds_read subtile ; stage 1 half-tile ; [lgkmcnt(8)] ; barrier ;
//   lgkmcnt(0) ; setprio+16 MFMA ; barrier}. ONE vmcnt(6) per K-tile (P4);
//   prefetch runs 1 tile + 3 half-tiles ahead (prologue vmcnt(4)/vmcnt(6)),
//   so that single vmcnt(6) retires the ENTIRE next tile. Epilogue drains
//   vmcnt(0) at t==nkt-2. LDS XOR-swizzled (0 bank conflicts, measured).
// Small GEMMs keep the proven 128x128 kernel.
// ---------------------------------------------------------------------------

typedef __bf16 bf16x8 __attribute__((ext_vector_type(8)));
typedef float floatx4 __attribute__((ext_vector_type(4)));
typedef unsigned short ushortx8 __attribute__((ext_vector_type(8)));

__device__ __forceinline__ unsigned short f2bf(float f) {
    unsigned int u = __builtin_bit_cast(unsigned int, f);
    u += 0x7FFFu + ((u >> 16) & 1u);   // round-to-nearest-even
    return (unsigned short)(u >> 16);
}

__device__ __forceinline__ void gld_lds16(const void* g, void* l) {
    __builtin_amdgcn_global_load_lds(
        (const __attribute__((address_space(1))) void*)g,
        (__attribute__((address_space(3))) void*)l,
        16, 0, 0);
}

__device__ __forceinline__ bf16x8 ldsv(const char* p) {
    return __builtin_bit_cast(bf16x8, *(const ushortx8*)p);
}

#define MFMA_BF16(a, b, c) __builtin_amdgcn_mfma_f32_16x16x32_bf16((a), (b), (c), 0, 0, 0)
#define SCHED0() __builtin_amdgcn_sched_barrier(0)

// ---------------------------------------------------------------------------
// Butterfly rows: R = C_0 C_1 ... C_9 (d=1024).
// mat 0 -> RVs (R_V with column k scaled by S[k]) bf16 ; mat 1 -> R_U bf16
// ---------------------------------------------------------------------------
__global__ __launch_bounds__(256) void butterfly_rows_kernel(
    const float* __restrict__ thetas_v, const float* __restrict__ thetas_u,
    const float* __restrict__ S,
    unsigned short* __restrict__ RVsb, unsigned short* __restrict__ RUb)
{
    const int d = 1024;
    __shared__ float w[1024];
    const int b   = blockIdx.x;
    const int mat = b >> 10;        // 0: V, 1: U
    const int row = b & 1023;
    const float* th = mat ? thetas_u : thetas_v;
    const int t = threadIdx.x;

    for (int i = t; i < d; i += 256) w[i] = (i == row) ? 1.f : 0.f;
    __syncthreads();

    for (int j = 0; j < 10; ++j) {
        const int sh = 9 - j;
        const int halfm1 = (1 << sh) - 1;
        for (int i = t; i < d / 2; i += 256) {
            const int blk = i >> sh;
            const int off = i & halfm1;
            const int p = (blk << (sh + 1)) + off;
            const int q = p + (halfm1 + 1);
            const float theta = th[j * (d / 2) + i];
            float s, c;
            __sincosf(theta, &s, &c);
            const float wp = w[p], wq = w[q];
            w[p] = c * wp + s * wq;
            w[q] = -s * wp + c * wq;
        }
        __syncthreads();
    }

    if (mat == 0) {
        for (int i = t; i < d; i += 256) RVsb[row * d + i] = f2bf(w[i] * S[i]);
    } else {
        for (int i = t; i < d; i += 256) RUb[row * d + i] = f2bf(w[i]);
    }
}

// ---------------------------------------------------------------------------
__global__ __launch_bounds__(256) void cvt_f32_bf16_x8(
    const float* __restrict__ src, unsigned short* __restrict__ dst)
{
    const size_t i = ((size_t)blockIdx.x * 256 + threadIdx.x) * 8;
    float4 a = *(const float4*)(src + i);
    float4 b = *(const float4*)(src + i + 4);
    ushortx8 o;
    o[0] = f2bf(a.x); o[1] = f2bf(a.y); o[2] = f2bf(a.z); o[3] = f2bf(a.w);
    o[4] = f2bf(b.x); o[5] = f2bf(b.y); o[6] = f2bf(b.z); o[7] = f2bf(b.w);
    *(ushortx8*)(dst + i) = o;
}

// ---------------------------------------------------------------------------
__global__ __launch_bounds__(256) void transpose_to_bf16(
    const float* __restrict__ src, unsigned short* __restrict__ dst,
    int rows, int cols)
{
    __shared__ float tile[32][33];
    const int tx = threadIdx.x & 31, ty = threadIdx.x >> 5;
    const int c0 = blockIdx.x * 32, r0 = blockIdx.y * 32;
    for (int i = 0; i < 32; i += 8)
        tile[ty + i][tx] = src[(size_t)(r0 + ty + i) * cols + c0 + tx];
    __syncthreads();
    for (int i = 0; i < 32; i += 8)
        dst[(size_t)(c0 + ty + i) * rows + r0 + tx] = f2bf(tile[tx][ty + i]);
}

// ---------------------------------------------------------------------------
// Small NT GEMM (the two 1024-class rotation GEMMs): 128x128 tile.
// ---------------------------------------------------------------------------
template <int EPI>
__global__ __launch_bounds__(256) void gemm_nt(
    const unsigned short* __restrict__ A,
    const unsigned short* __restrict__ B,
    float* __restrict__ Cf,
    unsigned short* __restrict__ Cb,
    const float* __restrict__ extra,
    int M, int N, int K)
{
    __shared__ __align__(16) unsigned short As[128 * 32];
    __shared__ __align__(16) unsigned short Bs[128 * 32];

    const int tid  = threadIdx.x;
    const int lane = tid & 63;
    const int wave = tid >> 6;
    const int wm = wave >> 1, wn = wave & 1;

    const int m0 = blockIdx.y * 128;
    const int n0 = blockIdx.x * 128;

    const int srow = wave * 32 + (lane >> 2);
    const int scol = (lane & 3) * 8;

    const unsigned short* gA = A + (size_t)(m0 + srow) * K + scol;
    const unsigned short* gB = B + (size_t)(n0 + srow) * K + scol;
    unsigned short* lA = As + wave * 32 * 32;
    unsigned short* lB = Bs + wave * 32 * 32;

    floatx4 acc[4][4];
#pragma unroll
    for (int i = 0; i < 4; ++i)
#pragma unroll
        for (int j = 0; j < 4; ++j) acc[i][j] = (floatx4)0.f;

    const int ar = lane & 15;
    const int ak = (lane >> 4) * 8;

    for (int kk = 0; kk < K; kk += 32) {
        gld_lds16(gA + kk, lA);
        gld_lds16(gA + kk + (size_t)16 * K, lA + 512);
        gld_lds16(gB + kk, lB);
        gld_lds16(gB + kk + (size_t)16 * K, lB + 512);
        __syncthreads();

        bf16x8 af[4], bfr[4];
#pragma unroll
        for (int tm = 0; tm < 4; ++tm)
            af[tm] = __builtin_bit_cast(bf16x8,
                *(const ushortx8*)&As[(wm * 64 + tm * 16 + ar) * 32 + ak]);
#pragma unroll
        for (int tn = 0; tn < 4; ++tn)
            bfr[tn] = __builtin_bit_cast(bf16x8,
                *(const ushortx8*)&Bs[(wn * 64 + tn * 16 + ar) * 32 + ak]);
#pragma unroll
        for (int tm = 0; tm < 4; ++tm)
#pragma unroll
            for (int tn = 0; tn < 4; ++tn)
                acc[tm][tn] = MFMA_BF16(af[tm], bfr[tn], acc[tm][tn]);
        __syncthreads();
    }

#pragma unroll
    for (int tm = 0; tm < 4; ++tm) {
#pragma unroll
        for (int tn = 0; tn < 4; ++tn) {
#pragma unroll
            for (int r = 0; r < 4; ++r) {
                const int row = m0 + wm * 64 + tm * 16 + (lane >> 4) * 4 + r;
                const int col = n0 + wn * 64 + tn * 16 + (lane & 15);
                const float v = acc[tm][tn][r];
                if (EPI == 1) {
                    Cf[(size_t)row * N + col] = v + extra[col];
                } else if (EPI == 2) {
                    Cb[(size_t)row * N + col] = f2bf(v);
                } else {
                    Cb[(size_t)row * N + col] = f2bf(v + extra[(size_t)row * N + col]);
                }
            }
        }
    }
}

// ---------------------------------------------------------------------------
// Large NT GEMM: 256x256 tile, BK=64, 512 threads (8 waves, 2M x 4N).
// LDS: As/Bs[2 dbuf][2 half][128][64] bf16, XOR-swizzled (linear dest +
// inverse-swizzled global source + swizzled ds_read).
// m201-faithful phases (per K-tile t; quad order Q00,Q01,Q11,Q10):
//   P1: rd A0+B0 (12 ds); stage (t+1).A1; lgkmcnt(8); bar; lgkm0; MFMA; bar
//   P2: rd B1 (4 ds);     stage (t+2).A0;             bar; lgkm0; MFMA; bar
//   P3: rd A1 (8 ds);     stage (t+2).B0;             bar; lgkm0; MFMA; bar
//   P4: no reads;         stage (t+2).B1; vmcnt(6);   bar;        MFMA; bar
// Prologue: stage t0{A0,B0,B1,A1}; vmcnt(4); stage t1{A0,B0,B1}; vmcnt(6).
// Queue proof: at P4 the vmcnt(6) (14 outstanding -> retire 8) retires
// exactly tile t+1's 4 half-tiles; every ds_read is covered, all WAR pairs
// are >=2 barriers apart. Drain: vmcnt(0) at t==nkt-2. nkt >= 2.
// EPI 1: f32 out + bias[col] ;  EPI 3: bf16 out + f32 extra[M,N]
// ---------------------------------------------------------------------------
#define RD_AF0() do { _Pragma("unroll") \
    for (int mf = 0; mf < 4; ++mf) { \
        af0[mf][0] = ldsv(Ad + arb + mf * 2048 + ca0); \
        af0[mf][1] = ldsv(Ad + arb + mf * 2048 + ca1); } } while (0)
#define RD_AF1() do { _Pragma("unroll") \
    for (int mf = 0; mf < 4; ++mf) { \
        af1[mf][0] = ldsv(Ad + 16384 + arb + mf * 2048 + ca0); \
        af1[mf][1] = ldsv(Ad + 16384 + arb + mf * 2048 + ca1); } } while (0)
#define RD_B0() do { _Pragma("unroll") \
    for (int nf = 0; nf < 2; ++nf) { \
        b0[nf][0] = ldsv(Bd + brb + nf * 2048 + ca0); \
        b0[nf][1] = ldsv(Bd + brb + nf * 2048 + ca1); } } while (0)
#define RD_B1() do { _Pragma("unroll") \
    for (int nf = 0; nf < 2; ++nf) { \
        b1[nf][0] = ldsv(Bd + 16384 + brb + nf * 2048 + ca0); \
        b1[nf][1] = ldsv(Bd + 16384 + brb + nf * 2048 + ca1); } } while (0)
#define MMQ(A_, B_, mo, no) do { \
    __builtin_amdgcn_s_setprio(1); \
    _Pragma("unroll") \
    for (int mf = 0; mf < 4; ++mf) \
        _Pragma("unroll") \
        for (int nf = 0; nf < 2; ++nf) { \
            acc[(mo) + mf][(no) + nf] = MFMA_BF16(A_[mf][0], B_[nf][0], acc[(mo) + mf][(no) + nf]); \
            acc[(mo) + mf][(no) + nf] = MFMA_BF16(A_[mf][1], B_[nf][1], acc[(mo) + mf][(no) + nf]); } \
    __builtin_amdgcn_s_setprio(0); } while (0)

template <int EPI>
__global__ __launch_bounds__(512, 2) void gemm256(
    const unsigned short* __restrict__ A,
    const unsigned short* __restrict__ B,
    float* __restrict__ Cf,
    unsigned short* __restrict__ Cb,
    const float* __restrict__ extra,
    int M, int N, int K, int swz_on)
{
    __shared__ __align__(16) unsigned short As[2][2][128][64];
    __shared__ __align__(16) unsigned short Bs[2][2][128][64];

    const int tid  = threadIdx.x;
    const int lane = tid & 63;
    const int wave = tid >> 6;
    const int wm = wave >> 2;      // 0..1
    const int wn = wave & 3;       // 0..3

    int bx = blockIdx.x, by = blockIdx.y;
    if (swz_on) {                  // XCD-aware bijective swizzle (nwg % 8 == 0)
        const int gx  = gridDim.x;
        const int nwg = gx * gridDim.y;
        const int f   = by * gx + bx;
        const int g   = (f & 7) * (nwg >> 3) + (f >> 3);
        bx = g % gx;
        by = g / gx;
    }
    const int m0 = by * 256;
    const int n0 = bx * 256;

    // ---- staging: linear LDS dest, inverse-swizzled global source
    const int srow  = tid >> 3;                          // 0..63 in a 64-row slab
    const int scolb = (tid & 7) << 4;                    // physical col byte
    const int scol  = (scolb ^ ((srow & 7) << 4)) >> 1;  // logical col (elems)
    const unsigned short* gA = A + (size_t)(m0 + srow) * K + scol;
    const unsigned short* gB = B + (size_t)(n0 + srow) * K + scol;
    char* lA = (char*)As + (wave << 10);                 // wave-uniform base
    char* lB = (char*)Bs + (wave << 10);
    const size_t rs64 = (size_t)64 * K;                  // 64-row stride

    // stage half-tile h (A or B) of K-tile src_t into buffer dbuf
    auto stA = [&](int src_t, int dbuf, int h) {
        const unsigned short* s = gA + (size_t)h * 2 * rs64 + (size_t)src_t * 64;
        char* l = lA + dbuf * 32768 + h * 16384;
        gld_lds16(s, l);
        gld_lds16(s + rs64, l + 8192);
    };
    auto stB = [&](int src_t, int dbuf, int h) {
        const unsigned short* s = gB + (size_t)h * 2 * rs64 + (size_t)src_t * 64;
        char* l = lB + dbuf * 32768 + h * 16384;
        gld_lds16(s, l);
        gld_lds16(s + rs64, l + 8192);
    };

    // ---- fragment read addressing (swizzled)
    const int fr  = lane & 15;
    const int kg  = lane >> 4;                 // 0..3 -> K elems 8*kg
    const int swz = (fr & 7) << 4;
    const int ca0 = (kg << 4) ^ swz;           // K-step 0 col byte
    const int ca1 = (64 + (kg << 4)) ^ swz;    // K-step 1 col byte
    const int arb = (wm * 64 + fr) * 128;      // A byte row base within half
    const int brb = (wn * 32 + fr) * 128;      // B byte row base within half

    floatx4 acc[8][4];
#pragma unroll
    for (int i = 0; i < 8; ++i)
#pragma unroll
        for (int j = 0; j < 4; ++j) acc[i][j] = (floatx4)0.f;

    const int nkt = K >> 6;

    // ---- prologue: 1 tile + 3 half-tiles ahead (m201: vmcnt(4) then vmcnt(6))
    stA(0, 0, 0); stB(0, 0, 0); stB(0, 0, 1); stA(0, 0, 1);
    asm volatile("s_waitcnt vmcnt(4)" ::: "memory");     // t0.A0, t0.B0 landed
    stA(1, 1, 0); stB(1, 1, 0); stB(1, 1, 1);
    asm volatile("s_waitcnt vmcnt(6)" ::: "memory");     // t0.B1, t0.A1 landed
    SCHED0();
    __builtin_amdgcn_s_barrier();
    SCHED0();

    for (int t = 0; t < nkt; ++t) {
        const int cb = t & 1, nb = cb ^ 1;
        const char* Ad = (const char*)As + cb * 32768;
        const char* Bd = (const char*)Bs + cb * 32768;

        bf16x8 af0[4][2], af1[4][2], b0[2][2], b1[2][2];

        // ==== P1: rd A0,B0 ; stage (t+1).A1 ; lgkm(8) ; Q00 ====
        RD_AF0(); RD_B0();
        if (t + 1 < nkt) stA(t + 1, nb, 1);
        asm volatile("s_waitcnt lgkmcnt(8)" ::: "memory");
        SCHED0();
        __builtin_amdgcn_s_barrier();
        asm volatile("s_waitcnt lgkmcnt(0)" ::: "memory");
        SCHED0();
        MMQ(af0, b0, 0, 0);
        SCHED0();
        __builtin_amdgcn_s_barrier();

        // ==== P2: rd B1 ; stage (t+2).A0 ; Q01 ====
        RD_B1();
        if (t + 2 < nkt) stA(t + 2, cb, 0);
        SCHED0();
        __builtin_amdgcn_s_barrier();
        asm volatile("s_waitcnt lgkmcnt(0)" ::: "memory");
        SCHED0();
        MMQ(af0, b1, 0, 2);
        SCHED0();
        __builtin_amdgcn_s_barrier();

        // ==== P3: rd A1 ; stage (t+2).B0 ; Q11 ====
        RD_AF1();
        if (t + 2 < nkt) stB(t + 2, cb, 0);
        SCHED0();
        __builtin_amdgcn_s_barrier();
        asm volatile("s_waitcnt lgkmcnt(0)" ::: "memory");
        SCHED0();
        MMQ(af1, b1, 4, 2);
        SCHED0();
        __builtin_amdgcn_s_barrier();

        // ==== P4: stage (t+2).B1 ; single vmcnt ; Q10 ====
        if (t + 2 < nkt) stB(t + 2, cb, 1);
        if (t == nkt - 2) {
            asm volatile("s_waitcnt vmcnt(0)" ::: "memory");   // drain: last tile fully landed
        } else if (t < nkt - 2) {
            asm volatile("s_waitcnt vmcnt(6)" ::: "memory");   // retires tile t+1 entirely
        }
        SCHED0();
        __builtin_amdgcn_s_barrier();
        SCHED0();
        MMQ(af1, b0, 4, 0);
        SCHED0();
        __builtin_amdgcn_s_barrier();
    }

    // epilogue: C/D layout col = lane&15, row = (lane>>4)*4 + r
    const int er4 = (lane >> 4) << 2;
    const int ec  = lane & 15;
#pragma unroll
    for (int Mq = 0; Mq < 2; ++Mq)
#pragma unroll
        for (int mf = 0; mf < 4; ++mf)
#pragma unroll
            for (int Nq = 0; Nq < 2; ++Nq)
#pragma unroll
                for (int nf = 0; nf < 2; ++nf)
#pragma unroll
                    for (int r = 0; r < 4; ++r) {
                        const int row = m0 + Mq * 128 + wm * 64 + mf * 16 + er4 + r;
                        const int col = n0 + Nq * 128 + wn * 32 + nf * 16 + ec;
                        const float v = acc[Mq * 4 + mf][Nq * 2 + nf][r];
                        if (EPI == 1) {
                            Cf[(size_t)row * N + col] = v + extra[col];
                        } else {
                            Cb[(size_t)row * N + col] = f2bf(v + extra[(size_t)row * N + col]);
                        }
                    }
    (void)M;
}

// ---------------------------------------------------------------------------
extern "C" void kernel_launch(void* const* d_in, const int* in_sizes, int n_in,
                              void* d_out, int out_size, void* d_ws, size_t ws_size,
                              hipStream_t stream)
{
    const int NB = 16384, DIN = 4096, DOUT = 4096, R = 1024;

    const float* x    = (const float*)d_in[0];
    const float* W    = (const float*)d_in[1];
    const float* bias = (const float*)d_in[2];
    const float* U    = (const float*)d_in[3];
    const float* S    = (const float*)d_in[4];
    const float* V    = (const float*)d_in[5];
    const float* th_u = (const float*)d_in[6];
    const float* th_v = (const float*)d_in[7];
    float* out = (float*)d_out;

    char* ws = (char*)d_ws;
    size_t off = 0;
    auto alloc = [&](size_t bytes) {
        char* p = ws + off;
        off += (bytes + 255) & ~(size_t)255;
        return p;
    };
    unsigned short* Xb   = (unsigned short*)alloc((size_t)NB * DIN * 2);
    unsigned short* Wctb = (unsigned short*)alloc((size_t)DOUT * DIN * 2);
    unsigned short* RVsb = (unsigned short*)alloc((size_t)R * R * 2);
    unsigned short* RUb  = (unsigned short*)alloc((size_t)R * R * 2);
    unsigned short* Tb   = (unsigned short*)alloc((size_t)R * R * 2);
    unsigned short* Ub   = (unsigned short*)alloc((size_t)DOUT * R * 2);
    unsigned short* Gb   = (unsigned short*)alloc((size_t)DOUT * R * 2);
    unsigned short* Vtb  = (unsigned short*)alloc((size_t)DIN * R * 2);
    if (off > ws_size) return;

    // 1. Butterfly rotations -> RVs (S-scaled) bf16, RU bf16
    butterfly_rows_kernel<<<2048, 256, 0, stream>>>(th_v, th_u, S, RVsb, RUb);

    // 2. Converts: x -> bf16, U -> bf16, V -> V^T bf16
    cvt_f32_bf16_x8<<<(NB * (size_t)DIN) / 2048, 256, 0, stream>>>(x, Xb);
    cvt_f32_bf16_x8<<<((size_t)DOUT * R) / 2048, 256, 0, stream>>>(U, Ub);
    transpose_to_bf16<<<dim3(DIN / 32, R / 32), 256, 0, stream>>>(V, Vtb, R, DIN);

    // 3. T[b,a] = sum_k RVs[b,k] * RU[a,k]
    gemm_nt<2><<<dim3(R / 128, R / 128), 256, 0, stream>>>(
        RVsb, RUb, nullptr, Tb, nullptr, R, R, R);

    // 4. G[o,b] = sum_a U[o,a] * T[b,a]
    gemm_nt<2><<<dim3(R / 128, DOUT / 128), 256, 0, stream>>>(
        Ub, Tb, nullptr, Gb, nullptr, DOUT, R, R);

    // 5. Wct[o,i] = W[o,i] + sum_b G[o,b] * Vt[i,b]   (256-tile, EPI3)
    gemm256<3><<<dim3(DIN / 256, DOUT / 256), 512, 0, stream>>>(
        Gb, Vtb, nullptr, Wctb, W, DOUT, DIN, R, 0);

    // 6. out[n,o] = sum_i Xb[n,i] * Wctb[o,i] + bias[o] (256-tile, EPI1, XCD swz)
    gemm256<1><<<dim3(DOUT / 256, NB / 256), 512, 0, stream>>>(
        Xb, Wctb, out, nullptr, bias, NB, DOUT, DIN, 1);
}